// Round 3
// baseline (153.663 us; speedup 1.0000x reference)
//
#include <hip/hip_runtime.h>
#include <hip/hip_bf16.h>
#include <math.h>

#define SLOPE 0.1f
#define B_ 16
#define C_ 64
#define H_ 160
#define W_ 160
#define HW_ (H_*W_)

// ws layout (floats): [0,9216) k[b][c][9] ; [9216,10240) att[b][c]
#define WS_K   0
#define WS_ATT 9216

typedef short bf16x8 __attribute__((ext_vector_type(8)));
typedef float f32x4  __attribute__((ext_vector_type(4)));

__device__ __forceinline__ float lrelu(float x) { return fmaxf(x, SLOPE * x); }

// round-to-nearest-even f32 -> bf16 (no NaN handling needed here)
__device__ __forceinline__ unsigned short f2bf(float x) {
  union { float f; unsigned u; } c; c.f = x;
  unsigned r = (c.u + 0x7fffu + ((c.u >> 16) & 1u)) >> 16;
  return (unsigned short)r;
}

__global__ __launch_bounds__(64) void prep_kernel(
    const float* __restrict__ deg,
    const float* __restrict__ W1,
    const float* __restrict__ W2,
    const float* __restrict__ Wd1,
    const float* __restrict__ Wd2,
    float* __restrict__ ws) {
  const int b = blockIdx.x;   // 0..15
  const int j = threadIdx.x;  // 0..63
  __shared__ float sd[64], sh[64], sa[8];
  sd[j] = deg[b * 64 + j];
  __syncthreads();

  float acc = 0.f;
  for (int i = 0; i < 64; ++i) acc = fmaf(sd[i], W1[j * 64 + i], acc);
  sh[j] = lrelu(acc);

  if (j < 8) {
    float s = 0.f;
    for (int i = 0; i < 64; ++i) s = fmaf(sd[i], Wd1[j * 64 + i], s);
    sa[j] = lrelu(s);
  }
  __syncthreads();

  float kv[9];
#pragma unroll
  for (int t = 0; t < 9; ++t) kv[t] = 0.f;
  for (int l = 0; l < 64; ++l) {
    float hl = sh[l];
#pragma unroll
    for (int t = 0; t < 9; ++t) kv[t] = fmaf(hl, W2[(j * 9 + t) * 64 + l], kv[t]);
  }
#pragma unroll
  for (int t = 0; t < 9; ++t) ws[WS_K + (b * 64 + j) * 9 + t] = kv[t];

  float s2 = 0.f;
#pragma unroll
  for (int r = 0; r < 8; ++r) s2 = fmaf(Wd2[j * 8 + r], sa[r], s2);
  ws[WS_ATT + b * 64 + j] = 1.f / (1.f + __expf(-s2));
}

// Fused main kernel:
//   Phase 1: depthwise 3x3 conv + lrelu -> bf16 T_lds[pixel][c]  (no acc pressure)
//   Phase 2: channel mix via MFMA 16x16x32 bf16 (A=Wc chunk, B=T_lds)
//   Epilogue: + bc + feat*att (fp32 re-read, mostly L2-hit), store.
// Block = 256 threads = 8x32 pixel tile of one batch. LDS 40 KB -> 4 blocks/CU.
#define TPAD 80  // ushorts per T row: 160 B stride, 16B-aligned, 4-way-bank reads

__global__ __launch_bounds__(256, 4) void main_kernel(
    const float* __restrict__ feat,
    const float* __restrict__ Wc,
    const float* __restrict__ bc,
    const float* __restrict__ ws,
    float* __restrict__ out) {
  __shared__ unsigned short T[256 * TPAD];

  const int tid = threadIdx.x;          // == pixel index in tile
  const int b  = blockIdx.z;
  const int x0 = blockIdx.x * 32, y0 = blockIdx.y * 8;
  const int px = tid & 31, py = (tid >> 5) & 7;
  const int x = x0 + px, y = y0 + py;

  const float* __restrict__ kkp  = ws + WS_K + b * 576;   // uniform -> s_load
  const float* __restrict__ attp = ws + WS_ATT + b * 64;
  const float* __restrict__ plane = feat + (size_t)(b * 64) * HW_;

  // ---- A-fragments (Wc rows for this wave's o-chunk), loaded up-front ----
  const int lane = tid & 63, wid = tid >> 6;
  const int nl = lane & 15, g = lane >> 4;   // n/m lane, k-group
  const int ochunk = wid * 16;
  union AF { bf16x8 v; unsigned short u[8]; };
  AF a0, a1;
  {
    const float* wr = Wc + (ochunk + nl) * 64 + 4 * g;
    const float4 w00 = *(const float4*)(wr);        // k = 4g..4g+3
    const float4 w01 = *(const float4*)(wr + 16);   // k = 16+4g..
    const float4 w10 = *(const float4*)(wr + 32);   // k = 32+4g..
    const float4 w11 = *(const float4*)(wr + 48);   // k = 48+4g..
    a0.u[0]=f2bf(w00.x); a0.u[1]=f2bf(w00.y); a0.u[2]=f2bf(w00.z); a0.u[3]=f2bf(w00.w);
    a0.u[4]=f2bf(w01.x); a0.u[5]=f2bf(w01.y); a0.u[6]=f2bf(w01.z); a0.u[7]=f2bf(w01.w);
    a1.u[0]=f2bf(w10.x); a1.u[1]=f2bf(w10.y); a1.u[2]=f2bf(w10.z); a1.u[3]=f2bf(w10.w);
    a1.u[4]=f2bf(w11.x); a1.u[5]=f2bf(w11.y); a1.u[6]=f2bf(w11.z); a1.u[7]=f2bf(w11.w);
  }

  // ---- Phase 1: conv fill ----
  const int om = max(y - 1, 0) * W_, oc = y * W_, op = min(y + 1, H_ - 1) * W_;
  const int xm = max(x - 1, 0), xp = min(x + 1, W_ - 1);
  const float Mt = (y > 0) ? 1.f : 0.f, Mb = (y < H_ - 1) ? 1.f : 0.f;
  const float Ml = (x > 0) ? 1.f : 0.f, Mr = (x < W_ - 1) ? 1.f : 0.f;
  const float Mtl = Mt * Ml, Mtr = Mt * Mr, Mbl = Mb * Ml, Mbr = Mb * Mr;

  for (int cc = 0; cc < 8; ++cc) {
    union { uint4 q; unsigned short u[8]; } pk;
#pragma unroll
    for (int i = 0; i < 8; ++i) {
      const int c = cc * 8 + i;
      const float* __restrict__ p = plane + (size_t)c * HW_;
      const float tl = p[om + xm] * Mtl, tc = p[om + x] * Mt, tr = p[om + xp] * Mtr;
      const float cl = p[oc + xm] * Ml,  ce = p[oc + x],      cr = p[oc + xp] * Mr;
      const float bl = p[op + xm] * Mbl, bb = p[op + x] * Mb, br = p[op + xp] * Mbr;
      const float* kc = kkp + c * 9;
      float s = tl * kc[0];
      s = fmaf(tc, kc[1], s); s = fmaf(tr, kc[2], s);
      s = fmaf(cl, kc[3], s); s = fmaf(ce, kc[4], s);
      s = fmaf(cr, kc[5], s); s = fmaf(bl, kc[6], s);
      s = fmaf(bb, kc[7], s); s = fmaf(br, kc[8], s);
      pk.u[i] = f2bf(lrelu(s));
    }
    *(uint4*)&T[tid * TPAD + cc * 8] = pk.q;  // 16B-aligned
  }
  __syncthreads();

  // ---- Phase 2: MFMA channel mix ----
  f32x4 acc[16];
#pragma unroll
  for (int nt = 0; nt < 16; ++nt) acc[nt] = (f32x4){0.f, 0.f, 0.f, 0.f};

#pragma unroll
  for (int nt = 0; nt < 16; ++nt) {
    const unsigned short* trow = &T[(nt * 16 + nl) * TPAD + 4 * g];
    union BF { bf16x8 v; uint2 q[2]; };
    BF b0, b1;
    b0.q[0] = *(const uint2*)(trow);        // k(c) = 4g..4g+3
    b0.q[1] = *(const uint2*)(trow + 16);   // k = 16+4g..
    b1.q[0] = *(const uint2*)(trow + 32);   // k = 32+4g..
    b1.q[1] = *(const uint2*)(trow + 48);   // k = 48+4g..
    acc[nt] = __builtin_amdgcn_mfma_f32_16x16x32_bf16(a0.v, b0.v, acc[nt], 0, 0, 0);
    acc[nt] = __builtin_amdgcn_mfma_f32_16x16x32_bf16(a1.v, b1.v, acc[nt], 0, 0, 0);
  }

  // ---- Epilogue: + bias + feat*att, store ----
  const int ob = ochunk + 4 * g;  // first of this lane's 4 output channels
  float bcv[4], attv[4];
#pragma unroll
  for (int j = 0; j < 4; ++j) { bcv[j] = bc[ob + j]; attv[j] = attp[ob + j]; }
  float* __restrict__ outb = out + (size_t)(b * 64) * HW_;
#pragma unroll
  for (int nt = 0; nt < 16; ++nt) {
    const int pix = nt * 16 + nl;
    const int off = (y0 + (pix >> 5)) * W_ + x0 + (pix & 31);
#pragma unroll
    for (int j = 0; j < 4; ++j) {
      const size_t o = (size_t)(ob + j);
      outb[o * HW_ + off] = acc[nt][j] + bcv[j] + plane[o * HW_ + off] * attv[j];
    }
  }
}

extern "C" void kernel_launch(void* const* d_in, const int* in_sizes, int n_in,
                              void* d_out, int out_size, void* d_ws, size_t ws_size,
                              hipStream_t stream) {
  const float* feat = (const float*)d_in[0];
  const float* deg  = (const float*)d_in[1];
  const float* W1   = (const float*)d_in[2];
  const float* W2   = (const float*)d_in[3];
  const float* Wc   = (const float*)d_in[4];
  const float* bc   = (const float*)d_in[5];
  const float* Wd1  = (const float*)d_in[6];
  const float* Wd2  = (const float*)d_in[7];
  float* out = (float*)d_out;
  float* ws  = (float*)d_ws;

  prep_kernel<<<dim3(B_), dim3(64), 0, stream>>>(deg, W1, W2, Wd1, Wd2, ws);
  main_kernel<<<dim3(5, 20, B_), dim3(256), 0, stream>>>(feat, Wc, bc, ws, out);
}

// Round 4
// 124.616 us; speedup vs baseline: 1.2331x; 1.2331x over previous
//
#include <hip/hip_runtime.h>
#include <hip/hip_bf16.h>
#include <math.h>

#define SLOPE 0.1f
#define B_ 16
#define C_ 64
#define H_ 160
#define W_ 160
#define HW_ (H_*W_)

// ws layout (floats): [0,9216) k[b][c][9] ; [9216,10240) att[b][c]
#define WS_K   0
#define WS_ATT 9216

typedef short bf16x8 __attribute__((ext_vector_type(8)));
typedef float f32x4  __attribute__((ext_vector_type(4)));

__device__ __forceinline__ float lrelu(float x) { return fmaxf(x, SLOPE * x); }
__device__ __forceinline__ unsigned short f2bf(float x) {
  union { float f; unsigned u; } c; c.f = x;
  return (unsigned short)((c.u + 0x7fffu + ((c.u >> 16) & 1u)) >> 16);
}
__device__ __forceinline__ float bf2f(unsigned short u) {
  union { unsigned u; float f; } c; c.u = ((unsigned)u) << 16; return c.f;
}

__global__ __launch_bounds__(64) void prep_kernel(
    const float* __restrict__ deg,
    const float* __restrict__ W1,
    const float* __restrict__ W2,
    const float* __restrict__ Wd1,
    const float* __restrict__ Wd2,
    float* __restrict__ ws) {
  const int b = blockIdx.x;   // 0..15
  const int j = threadIdx.x;  // 0..63
  __shared__ float sd[64], sh[64], sa[8];
  sd[j] = deg[b * 64 + j];
  __syncthreads();

  float acc = 0.f;
  for (int i = 0; i < 64; ++i) acc = fmaf(sd[i], W1[j * 64 + i], acc);
  sh[j] = lrelu(acc);

  if (j < 8) {
    float s = 0.f;
    for (int i = 0; i < 64; ++i) s = fmaf(sd[i], Wd1[j * 64 + i], s);
    sa[j] = lrelu(s);
  }
  __syncthreads();

  float kv[9];
#pragma unroll
  for (int t = 0; t < 9; ++t) kv[t] = 0.f;
  for (int l = 0; l < 64; ++l) {
    float hl = sh[l];
#pragma unroll
    for (int t = 0; t < 9; ++t) kv[t] = fmaf(hl, W2[(j * 9 + t) * 64 + l], kv[t]);
  }
#pragma unroll
  for (int t = 0; t < 9; ++t) ws[WS_K + (b * 64 + j) * 9 + t] = kv[t];

  float s2 = 0.f;
#pragma unroll
  for (int r = 0; r < 8; ++r) s2 = fmaf(Wd2[j * 8 + r], sa[r], s2);
  ws[WS_ATT + b * 64 + j] = 1.f / (1.f + __expf(-s2));
}

// Main kernel. Tile = 8 rows x 16 cols (128 px) of one batch image.
// Phase 1: each thread = (pixel quad q, 8-channel block cb); per channel:
//   {float, float4, float} x 3 rows -> 4 conv outputs -> bf16 into swizzled
//   T[pix][c] LDS; center taps into F[pix][c] (for the residual, no re-read).
// Phase 2: MFMA 16x16x32 bf16 channel mix from T.
// Epilogue: + bc + F*att, store.
// LDS 32 KB -> 4 blocks/CU at VGPR<=128.
__global__ __launch_bounds__(256, 4) void main_kernel(
    const float* __restrict__ feat,
    const float* __restrict__ Wc,
    const float* __restrict__ bc,
    const float* __restrict__ ws,
    float* __restrict__ out) {
  __shared__ unsigned short T[128 * 64];
  __shared__ unsigned short F[128 * 64];

  // Chunked XCD swizzle (3200 % 8 == 0): each XCD gets a contiguous strip
  // of tiles -> x/y-neighbor halo lines are L2-local.
  const int rb  = blockIdx.x;
  const int bid = (rb & 7) * 400 + (rb >> 3);
  const int b   = bid / 200;
  const int rem = bid - b * 200;
  const int ty  = rem / 10, tx = rem - ty * 10;
  const int x0 = tx * 16, y0 = ty * 8;
  const int tid = threadIdx.x;

  const float* __restrict__ kkp   = ws + WS_K + b * 576;   // uniform
  const float* __restrict__ attp  = ws + WS_ATT + b * 64;
  const float* __restrict__ plane = feat + (size_t)(b * 64) * HW_;

  const int lane = tid & 63, wid = tid >> 6;
  const int nl = lane & 15, g = lane >> 4;
  const int ochunk = wid * 16;

  // ---- A-fragments (Wc rows for this wave's o-chunk) ----
  union AF { bf16x8 v; unsigned short u[8]; };
  AF a0, a1;
  {
    const float* wr = Wc + (ochunk + nl) * 64 + 4 * g;
    const float4 w00 = *(const float4*)(wr);
    const float4 w01 = *(const float4*)(wr + 16);
    const float4 w10 = *(const float4*)(wr + 32);
    const float4 w11 = *(const float4*)(wr + 48);
    a0.u[0]=f2bf(w00.x); a0.u[1]=f2bf(w00.y); a0.u[2]=f2bf(w00.z); a0.u[3]=f2bf(w00.w);
    a0.u[4]=f2bf(w01.x); a0.u[5]=f2bf(w01.y); a0.u[6]=f2bf(w01.z); a0.u[7]=f2bf(w01.w);
    a1.u[0]=f2bf(w10.x); a1.u[1]=f2bf(w10.y); a1.u[2]=f2bf(w10.z); a1.u[3]=f2bf(w10.w);
    a1.u[4]=f2bf(w11.x); a1.u[5]=f2bf(w11.y); a1.u[6]=f2bf(w11.z); a1.u[7]=f2bf(w11.w);
  }

  // ---- Phase 1: conv fill ----
  const int q = tid & 31, cb = tid >> 5;     // 32 quads x 8 channel-blocks
  const int yy = y0 + (q >> 2);
  const int xb = x0 + (q & 3) * 4;
  const int om = max(yy - 1, 0) * W_, oc = yy * W_, op = min(yy + 1, H_ - 1) * W_;
  const float Mt = (yy > 0) ? 1.f : 0.f, Mb = (yy < H_ - 1) ? 1.f : 0.f;
  const float ml = (xb > 0) ? 1.f : 0.f, mr = (xb + 4 < W_) ? 1.f : 0.f;
  const int xl = max(xb - 1, 0), xr = min(xb + 4, W_ - 1);

  // k-coeff rows for this wave's two channel-blocks: wave-uniform -> s_load.
  const int wv = __builtin_amdgcn_readfirstlane(wid);
  const bool hi = (lane >= 32);                 // cb = 2*wv + hi
  const float* __restrict__ kA = kkp + (16 * wv) * 9;      // ch 16wv + i
  const float* __restrict__ kB = kkp + (16 * wv + 8) * 9;  // ch 16wv+8 + i

  union PK { uint4 qv; unsigned short u[8]; };
  PK pkT[4], pkF[4];

#pragma unroll
  for (int i = 0; i < 8; ++i) {
    const int c = cb * 8 + i;
    const float* __restrict__ p = plane + (size_t)c * HW_;
    float  Lt = p[om + xl]; const float4 Mtv = *(const float4*)(p + om + xb); float Rt = p[om + xr];
    float  Lc = p[oc + xl]; const float4 Mcv = *(const float4*)(p + oc + xb); float Rc = p[oc + xr];
    float  Lb = p[op + xl]; const float4 Mbv = *(const float4*)(p + op + xb); float Rb = p[op + xr];

    float k[9];
#pragma unroll
    for (int t = 0; t < 9; ++t) k[t] = hi ? kB[i * 9 + t] : kA[i * 9 + t];

    float at[6], ac[6], ab[6];
    at[0] = Lt * (Mt * ml); at[5] = Rt * (Mt * mr);
    at[1] = Mtv.x * Mt; at[2] = Mtv.y * Mt; at[3] = Mtv.z * Mt; at[4] = Mtv.w * Mt;
    ac[0] = Lc * ml;    ac[5] = Rc * mr;
    ac[1] = Mcv.x; ac[2] = Mcv.y; ac[3] = Mcv.z; ac[4] = Mcv.w;
    ab[0] = Lb * (Mb * ml); ab[5] = Rb * (Mb * mr);
    ab[1] = Mbv.x * Mb; ab[2] = Mbv.y * Mb; ab[3] = Mbv.z * Mb; ab[4] = Mbv.w * Mb;

#pragma unroll
    for (int j = 0; j < 4; ++j) {
      float s = at[j] * k[0];
      s = fmaf(at[j + 1], k[1], s); s = fmaf(at[j + 2], k[2], s);
      s = fmaf(ac[j],     k[3], s); s = fmaf(ac[j + 1], k[4], s);
      s = fmaf(ac[j + 2], k[5], s); s = fmaf(ab[j],     k[6], s);
      s = fmaf(ab[j + 1], k[7], s); s = fmaf(ab[j + 2], k[8], s);
      pkT[j].u[i] = f2bf(lrelu(s));
      pkF[j].u[i] = f2bf(ac[j + 1]);   // center tap (always interior-valid)
    }
  }

  // Swizzled writes: element (p,c) lives at ushort idx p*64 + ((c>>3)^e(p))*8 + (c&7)
#pragma unroll
  for (int j = 0; j < 4; ++j) {
    const int pp = 4 * q + j;
    const int e = (pp ^ (pp >> 3)) & 7;
    const int idx = pp * 64 + ((cb ^ e) << 3);
    *(uint4*)&T[idx] = pkT[j].qv;
    *(uint4*)&F[idx] = pkF[j].qv;
  }
  __syncthreads();

  // ---- Phase 2: MFMA channel mix ----
  f32x4 acc[8];
#pragma unroll
  for (int nt = 0; nt < 8; ++nt) acc[nt] = (f32x4){0.f, 0.f, 0.f, 0.f};

  union BFr { bf16x8 v; uint2 qv[2]; };
  const int lo = 4 * (g & 1);
  const int u0 = g >> 1;
#pragma unroll
  for (int nt = 0; nt < 8; ++nt) {
    const int pp = nt * 16 + nl;
    const int e = (pp ^ (pp >> 3)) & 7;
    const unsigned short* base = &T[pp * 64];
    BFr b0, b1;
    b0.qv[0] = *(const uint2*)&base[(((u0 + 0) ^ e) << 3) + lo];  // c = 4g+0..3
    b0.qv[1] = *(const uint2*)&base[(((u0 + 2) ^ e) << 3) + lo];  // c = 16+4g
    b1.qv[0] = *(const uint2*)&base[(((u0 + 4) ^ e) << 3) + lo];  // c = 32+4g
    b1.qv[1] = *(const uint2*)&base[(((u0 + 6) ^ e) << 3) + lo];  // c = 48+4g
    acc[nt] = __builtin_amdgcn_mfma_f32_16x16x32_bf16(a0.v, b0.v, acc[nt], 0, 0, 0);
    acc[nt] = __builtin_amdgcn_mfma_f32_16x16x32_bf16(a1.v, b1.v, acc[nt], 0, 0, 0);
  }

  // ---- Epilogue: + bias + F*att, store ----
  const int ob = ochunk + 4 * g;
  const float4 bcv = *(const float4*)(bc + ob);
  const float4 atv = *(const float4*)(attp + ob);
  float* __restrict__ outb = out + (size_t)(b * 64) * HW_;
  const int uf = (ob >> 3);  // = 2*wid + (g>>1)
#pragma unroll
  for (int nt = 0; nt < 8; ++nt) {
    const int pp = nt * 16 + nl;
    const int e = (pp ^ (pp >> 3)) & 7;
    union { uint2 qv; unsigned short u[4]; } fv;
    fv.qv = *(const uint2*)&F[pp * 64 + (((uf ^ e) << 3) + lo)];
    const int off = (y0 + nt) * W_ + x0 + nl;
    outb[(size_t)(ob + 0) * HW_ + off] = acc[nt][0] + bcv.x + bf2f(fv.u[0]) * atv.x;
    outb[(size_t)(ob + 1) * HW_ + off] = acc[nt][1] + bcv.y + bf2f(fv.u[1]) * atv.y;
    outb[(size_t)(ob + 2) * HW_ + off] = acc[nt][2] + bcv.z + bf2f(fv.u[2]) * atv.z;
    outb[(size_t)(ob + 3) * HW_ + off] = acc[nt][3] + bcv.w + bf2f(fv.u[3]) * atv.w;
  }
}

extern "C" void kernel_launch(void* const* d_in, const int* in_sizes, int n_in,
                              void* d_out, int out_size, void* d_ws, size_t ws_size,
                              hipStream_t stream) {
  const float* feat = (const float*)d_in[0];
  const float* deg  = (const float*)d_in[1];
  const float* W1   = (const float*)d_in[2];
  const float* W2   = (const float*)d_in[3];
  const float* Wc   = (const float*)d_in[4];
  const float* bc   = (const float*)d_in[5];
  const float* Wd1  = (const float*)d_in[6];
  const float* Wd2  = (const float*)d_in[7];
  float* out = (float*)d_out;
  float* ws  = (float*)d_ws;

  prep_kernel<<<dim3(B_), dim3(64), 0, stream>>>(deg, W1, W2, Wd1, Wd2, ws);
  main_kernel<<<dim3(3200), dim3(256), 0, stream>>>(feat, Wc, bc, ws, out);
}

// Round 5
// 79.045 us; speedup vs baseline: 1.9440x; 1.5765x over previous
//
#include <hip/hip_runtime.h>
#include <hip/hip_bf16.h>
#include <math.h>

#define SLOPE 0.1f
#define B_ 16
#define C_ 64
#define H_ 160
#define W_ 160
#define HW_ (H_*W_)

// ws layout (floats): [0,9216) k[b][c][9] ; [9216,10240) att[b][c]
#define WS_K   0
#define WS_ATT 9216

typedef short bf16x8 __attribute__((ext_vector_type(8)));
typedef float f32x4  __attribute__((ext_vector_type(4)));
typedef unsigned int uint2v __attribute__((ext_vector_type(2)));

__device__ __forceinline__ float lrelu(float x) { return fmaxf(x, SLOPE * x); }
__device__ __forceinline__ unsigned f2bf(float x) {
  union { float f; unsigned u; } c; c.f = x;
  return (c.u + 0x7fffu + ((c.u >> 16) & 1u)) >> 16;
}

__global__ __launch_bounds__(64) void prep_kernel(
    const float* __restrict__ deg,
    const float* __restrict__ W1,
    const float* __restrict__ W2,
    const float* __restrict__ Wd1,
    const float* __restrict__ Wd2,
    float* __restrict__ ws) {
  const int b = blockIdx.x;   // 0..15
  const int j = threadIdx.x;  // 0..63
  __shared__ float sd[64], sh[64], sa[8];
  sd[j] = deg[b * 64 + j];
  __syncthreads();

  float acc = 0.f;
  for (int i = 0; i < 64; ++i) acc = fmaf(sd[i], W1[j * 64 + i], acc);
  sh[j] = lrelu(acc);

  if (j < 8) {
    float s = 0.f;
    for (int i = 0; i < 64; ++i) s = fmaf(sd[i], Wd1[j * 64 + i], s);
    sa[j] = lrelu(s);
  }
  __syncthreads();

  float kv[9];
#pragma unroll
  for (int t = 0; t < 9; ++t) kv[t] = 0.f;
  for (int l = 0; l < 64; ++l) {
    float hl = sh[l];
#pragma unroll
    for (int t = 0; t < 9; ++t) kv[t] = fmaf(hl, W2[(j * 9 + t) * 64 + l], kv[t]);
  }
#pragma unroll
  for (int t = 0; t < 9; ++t) ws[WS_K + (b * 64 + j) * 9 + t] = kv[t];

  float s2 = 0.f;
#pragma unroll
  for (int r = 0; r < 8; ++r) s2 = fmaf(Wd2[j * 8 + r], sa[r], s2);
  ws[WS_ATT + b * 64 + j] = 1.f / (1.f + __expf(-s2));
}

// Tile = 8 rows x 16 cols (128 px) of one batch image.
// Phase 1: thread = (channel c = tid>>2, x-quad q = tid&3). Owns a 4-px-wide
//   x 8-row strip of channel c: loads 10 rows x {scalar,float4,scalar} = 30
//   INDEPENDENT loads in one burst, then 288 FMAs. Results (bf16) go to
//   subtiled LDS T' [cblk][pblk(=row)][16][16]; center taps to F' (same).
// Phase 2: MFMA 16x16x32 bf16; B-fragments via ds_read_b64_tr_b16 from T'
//   (lane addr = base + lane*8; offset imm walks subtiles).
// Epilogue: + bc + F'*att via one tr_read per row-tile, coalesced stores.
__global__ __launch_bounds__(256, 4) void main_kernel(
    const float* __restrict__ feat,
    const float* __restrict__ Wc,
    const float* __restrict__ bc,
    const float* __restrict__ ws,
    float* __restrict__ out) {
  __shared__ unsigned short Tq[8192];  // 16 KB: [4 cblk][8 pblk][16][16]
  __shared__ unsigned short Fq[8192];  // 16 KB: same layout

  // Chunked XCD swizzle (3200 % 8 == 0).
  const int rb  = blockIdx.x;
  const int bid = (rb & 7) * 400 + (rb >> 3);
  const int b   = bid / 200;
  const int rem = bid - b * 200;
  const int ty  = rem / 10, tx = rem - ty * 10;
  const int x0 = tx * 16, y0 = ty * 8;
  const int tid = threadIdx.x;

  const float* __restrict__ kkp   = ws + WS_K + b * 576;
  const float* __restrict__ attp  = ws + WS_ATT + b * 64;
  const float* __restrict__ plane = feat + (size_t)(b * 64) * HW_;

  // ================= Phase 1: conv, strip-mined =================
  const int c = tid >> 2, q = tid & 3;
  const int xb = x0 + q * 4;
  const int xl = max(xb - 1, 0), xr = min(xb + 4, W_ - 1);
  const float ml = (xb > 0) ? 1.f : 0.f;
  const float mr = (xb + 4 < W_) ? 1.f : 0.f;

  const float* __restrict__ p  = plane + (size_t)c * HW_;
  const float* __restrict__ kc = kkp + c * 9;
  const float4 k03 = *(const float4*)(kc);
  const float4 k47 = *(const float4*)(kc + 4);
  const float  k8  = kc[8];

  // 30 independent loads (one burst), then fold masks in place.
  float  Lr[10], Rr[10];
  float4 Mr[10];
#pragma unroll
  for (int r = 0; r < 10; ++r) {
    const int rg = y0 + r - 1;
    const int rc = min(max(rg, 0), H_ - 1);
    const float* rp = p + rc * W_;
    Lr[r] = rp[xl];
    Mr[r] = *(const float4*)(rp + xb);
    Rr[r] = rp[xr];
  }
#pragma unroll
  for (int r = 0; r < 10; ++r) {
    const int rg = y0 + r - 1;
    const float mrow = (rg >= 0 && rg < H_) ? 1.f : 0.f;
    Lr[r] *= mrow * ml;
    Mr[r].x *= mrow; Mr[r].y *= mrow; Mr[r].z *= mrow; Mr[r].w *= mrow;
    Rr[r] *= mrow * mr;
  }

  const int cblk = c >> 4, crow = c & 15;
  const int tbase = cblk * 2048 + crow * 16 + q * 4;  // ushort units
#pragma unroll
  for (int r = 0; r < 8; ++r) {
    // rows r (top), r+1 (center), r+2 (bottom); 6-wide windows
    const float t0 = Lr[r],   t1 = Mr[r].x,   t2 = Mr[r].y,   t3 = Mr[r].z,   t4 = Mr[r].w,   t5 = Rr[r];
    const float c0 = Lr[r+1], c1 = Mr[r+1].x, c2 = Mr[r+1].y, c3 = Mr[r+1].z, c4 = Mr[r+1].w, c5 = Rr[r+1];
    const float b0 = Lr[r+2], b1 = Mr[r+2].x, b2 = Mr[r+2].y, b3 = Mr[r+2].z, b4 = Mr[r+2].w, b5 = Rr[r+2];

    float s0 = t0 * k03.x;
    s0 = fmaf(t1, k03.y, s0); s0 = fmaf(t2, k03.z, s0);
    s0 = fmaf(c0, k03.w, s0); s0 = fmaf(c1, k47.x, s0);
    s0 = fmaf(c2, k47.y, s0); s0 = fmaf(b0, k47.z, s0);
    s0 = fmaf(b1, k47.w, s0); s0 = fmaf(b2, k8,    s0);
    float s1 = t1 * k03.x;
    s1 = fmaf(t2, k03.y, s1); s1 = fmaf(t3, k03.z, s1);
    s1 = fmaf(c1, k03.w, s1); s1 = fmaf(c2, k47.x, s1);
    s1 = fmaf(c3, k47.y, s1); s1 = fmaf(b1, k47.z, s1);
    s1 = fmaf(b2, k47.w, s1); s1 = fmaf(b3, k8,    s1);
    float s2 = t2 * k03.x;
    s2 = fmaf(t3, k03.y, s2); s2 = fmaf(t4, k03.z, s2);
    s2 = fmaf(c2, k03.w, s2); s2 = fmaf(c3, k47.x, s2);
    s2 = fmaf(c4, k47.y, s2); s2 = fmaf(b2, k47.z, s2);
    s2 = fmaf(b3, k47.w, s2); s2 = fmaf(b4, k8,    s2);
    float s3 = t3 * k03.x;
    s3 = fmaf(t4, k03.y, s3); s3 = fmaf(t5, k03.z, s3);
    s3 = fmaf(c3, k03.w, s3); s3 = fmaf(c4, k47.x, s3);
    s3 = fmaf(c5, k47.y, s3); s3 = fmaf(b3, k47.z, s3);
    s3 = fmaf(b4, k47.w, s3); s3 = fmaf(b5, k8,    s3);

    uint2v tq, fq;
    tq.x = f2bf(lrelu(s0)) | (f2bf(lrelu(s1)) << 16);
    tq.y = f2bf(lrelu(s2)) | (f2bf(lrelu(s3)) << 16);
    fq.x = f2bf(c1) | (f2bf(c2) << 16);   // center taps (interior rows, unmasked)
    fq.y = f2bf(c3) | (f2bf(c4) << 16);
    *(uint2v*)&Tq[tbase + r * 256] = tq;
    *(uint2v*)&Fq[tbase + r * 256] = fq;
  }
  __syncthreads();

  // ================= Phase 2: MFMA channel mix =================
  const int lane = tid & 63, wid = tid >> 6;
  const int nl = lane & 15, g = lane >> 4;
  const int ochunk = wid * 16;

  union AF { bf16x8 v; unsigned short u[8]; };
  AF a0, a1;
  {
    const float* wr = Wc + (ochunk + nl) * 64 + 4 * g;
    const float4 w00 = *(const float4*)(wr);
    const float4 w01 = *(const float4*)(wr + 16);
    const float4 w10 = *(const float4*)(wr + 32);
    const float4 w11 = *(const float4*)(wr + 48);
    a0.u[0]=f2bf(w00.x); a0.u[1]=f2bf(w00.y); a0.u[2]=f2bf(w00.z); a0.u[3]=f2bf(w00.w);
    a0.u[4]=f2bf(w01.x); a0.u[5]=f2bf(w01.y); a0.u[6]=f2bf(w01.z); a0.u[7]=f2bf(w01.w);
    a1.u[0]=f2bf(w10.x); a1.u[1]=f2bf(w10.y); a1.u[2]=f2bf(w10.z); a1.u[3]=f2bf(w10.w);
    a1.u[4]=f2bf(w11.x); a1.u[5]=f2bf(w11.y); a1.u[6]=f2bf(w11.z); a1.u[7]=f2bf(w11.w);
  }

  const unsigned t_lds = (unsigned)(uintptr_t)(&Tq[0]) + (unsigned)(lane * 8);
  const unsigned f_lds = (unsigned)(uintptr_t)(&Fq[0]) + (unsigned)(lane * 8) + (unsigned)(wid * 4096);

  f32x4 acc[8];
#pragma unroll
  for (int nt = 0; nt < 8; ++nt) acc[nt] = (f32x4){0.f, 0.f, 0.f, 0.f};

  union BU { bf16x8 v; uint2v qv[2]; };
#pragma unroll
  for (int nt = 0; nt < 8; ++nt) {
    uint2v r0, r1, r2, r3;
    asm volatile("ds_read_b64_tr_b16 %0, %1 offset:%2" : "=v"(r0) : "v"(t_lds), "i"(nt * 512));
    asm volatile("ds_read_b64_tr_b16 %0, %1 offset:%2" : "=v"(r1) : "v"(t_lds), "i"(4096 + nt * 512));
    asm volatile("ds_read_b64_tr_b16 %0, %1 offset:%2" : "=v"(r2) : "v"(t_lds), "i"(8192 + nt * 512));
    asm volatile("ds_read_b64_tr_b16 %0, %1 offset:%2" : "=v"(r3) : "v"(t_lds), "i"(12288 + nt * 512));
    asm volatile("s_waitcnt lgkmcnt(0)" ::: "memory");
    __builtin_amdgcn_sched_barrier(0);
    BU bu0, bu1;
    bu0.qv[0] = r0; bu0.qv[1] = r1;   // k = 4g+j  and  16+4g+j
    bu1.qv[0] = r2; bu1.qv[1] = r3;   // k = 32+4g+j and 48+4g+j
    acc[nt] = __builtin_amdgcn_mfma_f32_16x16x32_bf16(a0.v, bu0.v, acc[nt], 0, 0, 0);
    acc[nt] = __builtin_amdgcn_mfma_f32_16x16x32_bf16(a1.v, bu1.v, acc[nt], 0, 0, 0);
  }

  // ================= Epilogue =================
  const int ob = ochunk + 4 * g;
  const float4 bcv = *(const float4*)(bc + ob);
  const float4 atv = *(const float4*)(attp + ob);
  float* __restrict__ outb = out + (size_t)(b * 64) * HW_;
#pragma unroll
  for (int nt = 0; nt < 8; ++nt) {
    uint2v fr;
    asm volatile("ds_read_b64_tr_b16 %0, %1 offset:%2" : "=v"(fr) : "v"(f_lds), "i"(nt * 512));
    asm volatile("s_waitcnt lgkmcnt(0)" ::: "memory");
    __builtin_amdgcn_sched_barrier(0);
    const float f0 = __uint_as_float((fr.x & 0xffffu) << 16);
    const float f1 = __uint_as_float((fr.x >> 16) << 16);
    const float f2 = __uint_as_float((fr.y & 0xffffu) << 16);
    const float f3 = __uint_as_float((fr.y >> 16) << 16);
    const int off = (y0 + nt) * W_ + x0 + nl;
    outb[(size_t)(ob + 0) * HW_ + off] = acc[nt][0] + bcv.x + f0 * atv.x;
    outb[(size_t)(ob + 1) * HW_ + off] = acc[nt][1] + bcv.y + f1 * atv.y;
    outb[(size_t)(ob + 2) * HW_ + off] = acc[nt][2] + bcv.z + f2 * atv.z;
    outb[(size_t)(ob + 3) * HW_ + off] = acc[nt][3] + bcv.w + f3 * atv.w;
  }
}

extern "C" void kernel_launch(void* const* d_in, const int* in_sizes, int n_in,
                              void* d_out, int out_size, void* d_ws, size_t ws_size,
                              hipStream_t stream) {
  const float* feat = (const float*)d_in[0];
  const float* deg  = (const float*)d_in[1];
  const float* W1   = (const float*)d_in[2];
  const float* W2   = (const float*)d_in[3];
  const float* Wc   = (const float*)d_in[4];
  const float* bc   = (const float*)d_in[5];
  const float* Wd1  = (const float*)d_in[6];
  const float* Wd2  = (const float*)d_in[7];
  float* out = (float*)d_out;
  float* ws  = (float*)d_ws;

  prep_kernel<<<dim3(B_), dim3(64), 0, stream>>>(deg, W1, W2, Wd1, Wd2, ws);
  main_kernel<<<dim3(3200), dim3(256), 0, stream>>>(feat, Wc, bc, ws, out);
}